// Round 4
// baseline (975.382 us; speedup 1.0000x reference)
//
#include <hip/hip_runtime.h>
#include <math.h>

// Sizes (fixed by the problem)
#define VOCAB 50000
#define EDIM  200
#define HDIM  256
#define G3    768      // 3*H
#define NSEQ1 4096     // B*R*S word sequences
#define T1    32       // W
#define NSEQ2 256      // B*R sentence sequences
#define T2    16       // S
#define NSEQ3 16       // B review sequences
#define T3    16       // R

using bf16x8 = __attribute__((ext_vector_type(8))) short;
using f32x4  = __attribute__((ext_vector_type(4))) float;

__device__ __forceinline__ float sigmoid_f(float x) {
    return 1.0f / (1.0f + __expf(-x));
}
__device__ __forceinline__ float tanh_f(float x) {
    return 1.0f - 2.0f / (__expf(2.0f * x) + 1.0f);
}
// f32 -> bf16 (RNE)
__device__ __forceinline__ short f2b(float f) {
    unsigned u = __float_as_uint(f);
    unsigned r = (u + 0x7fffu + ((u >> 16) & 1u)) >> 16;
    return (short)r;
}
__device__ __forceinline__ float b2f(unsigned short v) {
    return __uint_as_float((unsigned)v << 16);
}
// async global->LDS, 16B per lane; dst must be wave-uniform (HW adds lane*16)
__device__ __forceinline__ void gload_lds16(const void* g, void* l) {
    __builtin_amdgcn_global_load_lds(
        (const __attribute__((address_space(1))) void*)g,
        (__attribute__((address_space(3))) void*)l, 16, 0, 0);
}

// ---------------------------------------------------------------------------
// Convert f32 [R][Kin] -> bf16 [R][Kpad], zero pad.
// ---------------------------------------------------------------------------
__global__ void convert_pad(const float* __restrict__ src, short* __restrict__ dst,
                            int Kin, int Kpad) {
    const int r = blockIdx.x;
    for (int k = threadIdx.x; k < Kpad; k += blockDim.x)
        dst[(size_t)r * Kpad + k] = (k < Kin) ? f2b(src[(size_t)r * Kin + k]) : (short)0;
}

// ---------------------------------------------------------------------------
// C[M,768] = A[M,Keff] @ WB[768,KPAD]^T + bias  via bf16 MFMA.
// KC=KPAD/32. AF32: A is f32 (else bf16). CBF16: C bf16 (else f32).
// Block 512 (8 waves), wave = M-tile, 12 N-tiles (BN=192). grid (ceil(M/128),4).
// ---------------------------------------------------------------------------
template <int KC, bool AF32, bool CBF16>
__global__ __launch_bounds__(512) void gemm_mfma(
    const void* __restrict__ Av, const short* __restrict__ WB,
    const float* __restrict__ bias, void* __restrict__ Cv,
    int M, int Keff) {
    constexpr int KPAD  = KC * 32;
    constexpr int CELLS = KPAD / 8;
    __shared__ short As[128 * 256];          // 64 KB
    const int tid = threadIdx.x;
    const int m0 = blockIdx.x * 128;
    const int n0 = blockIdx.y * 192;

    // ---- stage A (convert if f32), 16B-cell XOR swizzle both sides ----
    {
        const int row  = tid >> 2;
        const int c0   = (tid & 3) * 8;
        const int rowg = m0 + row;
        const int vcell = Keff >> 3;
        for (int i = 0; i < 8; i++) {
            const int c = c0 + i;
            if (c >= CELLS) break;
            bf16x8 v;
            if (rowg < M && c < vcell) {
                if constexpr (AF32) {
                    const float* ap = (const float*)Av + (size_t)rowg * Keff + c * 8;
                    const float4 x = *(const float4*)ap;
                    const float4 y = *(const float4*)(ap + 4);
                    v[0] = f2b(x.x); v[1] = f2b(x.y); v[2] = f2b(x.z); v[3] = f2b(x.w);
                    v[4] = f2b(y.x); v[5] = f2b(y.y); v[6] = f2b(y.z); v[7] = f2b(y.w);
                } else {
                    const short* ap = (const short*)Av + (size_t)rowg * Keff + c * 8;
                    v = *(const bf16x8*)ap;
                }
            } else {
                v = (bf16x8)(short)0;
            }
            *(bf16x8*)&As[row * 256 + ((c ^ (row & 7)) << 3)] = v;
        }
    }
    __syncthreads();

    const int w  = tid >> 6;
    const int l  = tid & 63;
    const int lr = l & 15, lg = l >> 4;

    bf16x8 af[KC];
    {
        const int row = (w << 4) + lr;
#pragma unroll
        for (int kc = 0; kc < KC; kc++) {
            const int cell = kc * 4 + lg;
            af[kc] = *(const bf16x8*)&As[row * 256 + ((cell ^ (row & 7)) << 3)];
        }
    }
    f32x4 acc[12];
#pragma unroll
    for (int nt = 0; nt < 12; nt++) acc[nt] = (f32x4){0.f, 0.f, 0.f, 0.f};
#pragma unroll
    for (int nt = 0; nt < 12; nt++) {
        const short* wb = WB + (size_t)(n0 + nt * 16 + lr) * KPAD + lg * 8;
#pragma unroll
        for (int kc = 0; kc < KC; kc++) {
            bf16x8 bf = *(const bf16x8*)(wb + kc * 32);
            acc[nt] = __builtin_amdgcn_mfma_f32_16x16x32_bf16(af[kc], bf, acc[nt], 0, 0, 0);
        }
    }
    // D layout: col=lane&15, row=(lane>>4)*4+q
#pragma unroll
    for (int nt = 0; nt < 12; nt++) {
        const int col = n0 + nt * 16 + lr;
        const float bv = bias[col];
#pragma unroll
        for (int q = 0; q < 4; q++) {
            const int row = m0 + (w << 4) + lg * 4 + q;
            if (row < M) {
                const float o = acc[nt][q] + bv;
                if constexpr (CBF16) ((short*)Cv)[(size_t)row * G3 + col] = f2b(o);
                else                 ((float*)Cv)[(size_t)row * G3 + col] = o;
            }
        }
    }
}

// ---------------------------------------------------------------------------
// MFMA GRU, TM=16 seqs/block, block 512 (8 waves). gx rows are bf16 (1536 B).
// Double-buffered gx tile staged via global_load_lds with source-side XOR
// swizzle (LDS dest linear; 16B cell ^= row&7; read applies same XOR).
// Wave w owns triples tt in {2w,2w+1}; phase B fully in-register; h f32 in
// regs, bf16 mirror in swizzled LDS for next step's MFMA A-fragments.
// ---------------------------------------------------------------------------
__global__ __launch_bounds__(512) void gru_mfma(
    const int* __restrict__ idx,        // null => dense rows (n0+s)*T + t
    const short* __restrict__ gxb,      // bf16 row table (P or gx dense)
    const short* __restrict__ WB,       // [768][256] bf16
    const float* __restrict__ bhh,
    float* __restrict__ hf32,           // optional [N][256]
    short* __restrict__ hb16,           // optional [N][256]
    int T) {
    __shared__ short hsB[16 * 256];     // 8 KB
    __shared__ short gxs[2][16 * 768];  // 2 x 24 KB
    const int tid = threadIdx.x;
    const int n0 = blockIdx.x * 16;
    const int w  = tid >> 6, l = tid & 63;
    const int lr = l & 15, lg = l >> 4;
    const int tt0 = w * 2;

    for (int i = tid; i < 16 * 256; i += 512) hsB[i] = 0;

    float bR[2], bZ[2], bN[2];
#pragma unroll
    for (int ti = 0; ti < 2; ti++) {
        const int jj = (tt0 + ti) * 16 + lr;
        bR[ti] = bhh[jj]; bZ[ti] = bhh[256 + jj]; bN[ti] = bhh[512 + jj];
    }
    float hreg[2][4] = {};

    // ---- stage helper (inlined twice below) ----
    // tile = 16 rows x 1536 B = 24576 B; 512 thr x 3 x 16 B.
    auto stage = [&](short* dstbase, int t) {
#pragma unroll
        for (int it = 0; it < 3; it++) {
            const int g = it * 8192 + (tid << 4);   // byte in tile
            const int s = g / 1536;
            const int cb = g - s * 1536;
            size_t rowbase;
            if (idx) {
                int tk = idx[(size_t)(n0 + s) * T + t];
                tk = min(max(tk, 0), VOCAB - 1);
                rowbase = (size_t)tk * 1536;
            } else {
                rowbase = ((size_t)(n0 + s) * T + t) * 1536;
            }
            const int cell = cb >> 4;
            const int sb = ((cell ^ (s & 7)) << 4) | (cb & 15);
            const char* src = (const char*)gxb + rowbase + sb;
            char* dst = (char*)dstbase + it * 8192 + (w << 10);  // wave-uniform
            gload_lds16(src, dst);
        }
    };
    auto gx_at = [&](const short* buf, int s, int col) -> float {
        const int cb = col << 1;
        const int addr = s * 1536 + ((((cb >> 4) ^ (s & 7)) << 4) | (cb & 15));
        return b2f(*(const unsigned short*)((const char*)buf + addr));
    };

    stage(gxs[0], 0);
    __syncthreads();    // drains vmcnt: buf0 ready; hsB zeros visible

    int cur = 0;
    for (int t = 0; t < T; t++) {
        // 1) prefetch next gx tile (completes during MFMA phase)
        if (t + 1 < T) stage(gxs[cur ^ 1], t + 1);

        // 2) A-fragments from swizzled bf16 h
        bf16x8 af[8];
#pragma unroll
        for (int kc = 0; kc < 8; kc++) {
            const int cell = kc * 4 + lg;
            af[kc] = *(const bf16x8*)&hsB[lr * 256 + ((cell ^ (lr & 7)) << 3)];
        }

        // 3) MFMA: 2 triples x 3 gates x 8 K = 48; weights stream from L2
        f32x4 acc[2][3];
#pragma unroll
        for (int ti = 0; ti < 2; ti++)
#pragma unroll
            for (int g = 0; g < 3; g++) acc[ti][g] = (f32x4){0.f, 0.f, 0.f, 0.f};
#pragma unroll
        for (int ti = 0; ti < 2; ti++) {
#pragma unroll
            for (int g = 0; g < 3; g++) {
                const short* wb = WB + (size_t)(g * 256 + (tt0 + ti) * 16 + lr) * 256 + lg * 8;
#pragma unroll
                for (int kc = 0; kc < 8; kc++) {
                    bf16x8 bf = *(const bf16x8*)(wb + kc * 32);
                    acc[ti][g] = __builtin_amdgcn_mfma_f32_16x16x32_bf16(af[kc], bf, acc[ti][g], 0, 0, 0);
                }
            }
        }
        __syncthreads();   // af reads done everywhere; gx(t) resident

        // 4) phase B: gates in-register; gx from LDS bf16
#pragma unroll
        for (int ti = 0; ti < 2; ti++) {
            const int jj = (tt0 + ti) * 16 + lr;
#pragma unroll
            for (int q = 0; q < 4; q++) {
                const int s = lg * 4 + q;
                const float xr = gx_at(gxs[cur], s, jj);
                const float xz = gx_at(gxs[cur], s, 256 + jj);
                const float xn = gx_at(gxs[cur], s, 512 + jj);
                const float r = sigmoid_f(xr + acc[ti][0][q] + bR[ti]);
                const float z = sigmoid_f(xz + acc[ti][1][q] + bZ[ti]);
                const float n = tanh_f(xn + r * (acc[ti][2][q] + bN[ti]));
                const float h = (1.f - z) * n + z * hreg[ti][q];
                hreg[ti][q] = h;
                hsB[s * 256 + (((jj >> 3) ^ (s & 7)) << 3) + (jj & 7)] = f2b(h);
            }
        }
        __syncthreads();   // hsB complete for next step
        cur ^= 1;
    }

#pragma unroll
    for (int ti = 0; ti < 2; ti++) {
        const int jj = (tt0 + ti) * 16 + lr;
#pragma unroll
        for (int q = 0; q < 4; q++) {
            const int s = lg * 4 + q;
            const size_t o = (size_t)(n0 + s) * HDIM + jj;
            if (hf32) hf32[o] = hreg[ti][q];
            if (hb16) hb16[o] = f2b(hreg[ti][q]);
        }
    }
}

// ---------------------------------------------------------------------------
// MLP head (f32, tiny)
// ---------------------------------------------------------------------------
__global__ __launch_bounds__(128) void mlp_head(
    const float* __restrict__ hin, const float* __restrict__ W1,
    const float* __restrict__ b1, const float* __restrict__ W2,
    const float* __restrict__ b2, float* __restrict__ out) {
    const int row = blockIdx.x;
    const int gg = threadIdx.x;
    const float* h = hin + (size_t)row * HDIM;
    const float* wv1 = W1 + (size_t)gg * HDIM;
    float acc = 0.f;
#pragma unroll 4
    for (int k = 0; k < HDIM; k += 4) {
        const float4 hv = *(const float4*)&h[k];
        const float4 wv = *(const float4*)&wv1[k];
        acc += hv.x * wv.x; acc += hv.y * wv.y;
        acc += hv.z * wv.z; acc += hv.w * wv.w;
    }
    acc += b1[gg];
    const float alpha = 1.6732632423543772f;
    const float scale = 1.0507009873554805f;
    const float s = scale * (acc > 0.f ? acc : alpha * expm1f(acc));
    float v = s * W2[gg];

    __shared__ float red[128];
    red[gg] = v;
    __syncthreads();
    if (gg < 64) {
        float x = red[gg] + red[gg + 64];
#pragma unroll
        for (int off = 32; off; off >>= 1) x += __shfl_down(x, off);
        if (gg == 0) out[row] = x + b2[0];
    }
}

// ---------------------------------------------------------------------------
extern "C" void kernel_launch(void* const* d_in, const int* in_sizes, int n_in,
                              void* d_out, int out_size, void* d_ws, size_t ws_size,
                              hipStream_t stream) {
    const int*   idx    = (const int*)d_in[0];
    const float* emb    = (const float*)d_in[1];
    const float* w_Wih  = (const float*)d_in[2];
    const float* w_Whh  = (const float*)d_in[3];
    const float* w_bih  = (const float*)d_in[4];
    const float* w_bhh  = (const float*)d_in[5];
    const float* s_Wih  = (const float*)d_in[6];
    const float* s_Whh  = (const float*)d_in[7];
    const float* s_bih  = (const float*)d_in[8];
    const float* s_bhh  = (const float*)d_in[9];
    const float* r_Wih  = (const float*)d_in[10];
    const float* r_Whh  = (const float*)d_in[11];
    const float* r_bih  = (const float*)d_in[12];
    const float* r_bhh  = (const float*)d_in[13];
    const float* rfc_W1 = (const float*)d_in[14];
    const float* rfc_b1 = (const float*)d_in[15];
    const float* rfc_W2 = (const float*)d_in[16];
    const float* rfc_b2 = (const float*)d_in[17];
    const float* pfc_W1 = (const float*)d_in[18];
    const float* pfc_b1 = (const float*)d_in[19];
    const float* pfc_W2 = (const float*)d_in[20];
    const float* pfc_b2 = (const float*)d_in[21];

    float* out = (float*)d_out;      // [0..15] b_stars, [16..271] r_stars

    // ---- workspace layout ----
    short* sws = (short*)d_ws;
    short* Pb      = sws;                                  // 50000*768 bf16
    short* gx2b    = Pb      + (size_t)VOCAB * G3;         // 4096*768
    short* gx3b    = gx2b    + (size_t)NSEQ1 * G3;         // 256*768
    short* WhhB_w  = gx3b    + (size_t)NSEQ2 * G3;         // 768*256
    short* WihB_w  = WhhB_w  + (size_t)G3 * HDIM;          // 768*224
    short* sWihB   = WihB_w  + (size_t)G3 * 224;
    short* sWhhB   = sWihB   + (size_t)G3 * HDIM;
    short* rWihB   = sWhhB   + (size_t)G3 * HDIM;
    short* rWhhB   = rWihB   + (size_t)G3 * HDIM;
    short* sent_hB = rWhhB   + (size_t)G3 * HDIM;          // 4096*256
    short* rev_hB  = sent_hB + (size_t)NSEQ1 * HDIM;       // 256*256
    float* fws     = (float*)(rev_hB + (size_t)NSEQ2 * HDIM);
    float* rev_h   = fws;                                  // 256*256 f32
    float* biz_h   = rev_h + (size_t)NSEQ2 * HDIM;         // 16*256 f32

    // ---- weight conversions ----
    convert_pad<<<G3, 256, 0, stream>>>(w_Whh, WhhB_w, HDIM, HDIM);
    convert_pad<<<G3, 256, 0, stream>>>(w_Wih, WihB_w, EDIM, 224);
    convert_pad<<<G3, 256, 0, stream>>>(s_Wih, sWihB, HDIM, HDIM);
    convert_pad<<<G3, 256, 0, stream>>>(s_Whh, sWhhB, HDIM, HDIM);
    convert_pad<<<G3, 256, 0, stream>>>(r_Wih, rWihB, HDIM, HDIM);
    convert_pad<<<G3, 256, 0, stream>>>(r_Whh, rWhhB, HDIM, HDIM);

    // 1) Pb = bf16(emb @ w_Wih^T + w_bih)  [50000 x 768]
    gemm_mfma<7, true, true><<<dim3((VOCAB + 127) / 128, 4), 512, 0, stream>>>(
        emb, WihB_w, w_bih, Pb, VOCAB, EDIM);

    // 2) Word-level GRU (gather): 4096 seqs x 32 steps -> sent_hB
    gru_mfma<<<NSEQ1 / 16, 512, 0, stream>>>(
        idx, Pb, WhhB_w, w_bhh, nullptr, sent_hB, T1);

    // 3) gx2b = bf16(sent_h @ s_Wih^T + s_bih)  [4096 x 768]
    gemm_mfma<8, false, true><<<dim3(NSEQ1 / 128, 4), 512, 0, stream>>>(
        sent_hB, sWihB, s_bih, gx2b, NSEQ1, HDIM);

    // 4) Sentence-level GRU (dense): 256 seqs x 16 steps -> rev_h(+bf16)
    gru_mfma<<<NSEQ2 / 16, 512, 0, stream>>>(
        nullptr, gx2b, sWhhB, s_bhh, rev_h, rev_hB, T2);

    // 5) r_stars -> out[16..271]
    mlp_head<<<NSEQ2, 128, 0, stream>>>(
        rev_h, rfc_W1, rfc_b1, rfc_W2, rfc_b2, out + 16);

    // 6) gx3b = bf16(rev_h @ r_Wih^T + r_bih)  [256 x 768]
    gemm_mfma<8, false, true><<<dim3(2, 4), 512, 0, stream>>>(
        rev_hB, rWihB, r_bih, gx3b, NSEQ2, HDIM);

    // 7) Review-level GRU (dense): 16 seqs x 16 steps -> biz_h
    gru_mfma<<<1, 512, 0, stream>>>(
        nullptr, gx3b, rWhhB, r_bhh, biz_h, nullptr, T3);

    // 8) b_stars -> out[0..15]
    mlp_head<<<NSEQ3, 128, 0, stream>>>(
        biz_h, pfc_W1, pfc_b1, pfc_W2, pfc_b2, out);
}

// Round 6
// 760.042 us; speedup vs baseline: 1.2833x; 1.2833x over previous
//
#include <hip/hip_runtime.h>
#include <math.h>

// Sizes (fixed by the problem)
#define VOCAB 50000
#define EDIM  200
#define HDIM  256
#define G3    768      // 3*H
#define NSEQ1 4096     // B*R*S word sequences
#define T1    32       // W
#define NSEQ2 256      // B*R sentence sequences
#define T2    16       // S
#define NSEQ3 16       // B review sequences
#define T3    16       // R

using bf16x8 = __attribute__((ext_vector_type(8))) short;
using f32x4  = __attribute__((ext_vector_type(4))) float;

__device__ __forceinline__ float sigmoid_f(float x) {
    return 1.0f / (1.0f + __expf(-x));
}
__device__ __forceinline__ float tanh_f(float x) {
    return 1.0f - 2.0f / (__expf(2.0f * x) + 1.0f);
}
// f32 -> bf16 (RNE)
__device__ __forceinline__ short f2b(float f) {
    unsigned u = __float_as_uint(f);
    unsigned r = (u + 0x7fffu + ((u >> 16) & 1u)) >> 16;
    return (short)r;
}
__device__ __forceinline__ float b2f(unsigned short v) {
    return __uint_as_float((unsigned)v << 16);
}
// barrier that drains ONLY lgkmcnt (LDS) — leaves global loads in flight
__device__ __forceinline__ void lds_barrier() {
    asm volatile("s_waitcnt lgkmcnt(0)\n\ts_barrier" ::: "memory");
}

// ---------------------------------------------------------------------------
// Batched f32 -> bf16 conversions (zero-padded): one launch for all 6 weights.
// ---------------------------------------------------------------------------
struct CvtJob { const float* src; short* dst; int kin; int kpad; };
struct CvtJobs { CvtJob j[6]; };

__global__ void convert6(CvtJobs jobs) {
    const CvtJob jb = jobs.j[blockIdx.y];
    const int r = blockIdx.x;
    for (int k = threadIdx.x; k < jb.kpad; k += blockDim.x)
        jb.dst[(size_t)r * jb.kpad + k] =
            (k < jb.kin) ? f2b(jb.src[(size_t)r * jb.kin + k]) : (short)0;
}

// ---------------------------------------------------------------------------
// C[M,768] = A[M,Keff] @ WB[768,KPAD]^T + bias  via bf16 MFMA.
// KC=KPAD/32. AF32: A f32 (else bf16). CBF16: C bf16 (else f32).
// Block 512 (8 waves), wave = M-tile, 12 N-tiles. grid (ceil(M/128), 4).
// ---------------------------------------------------------------------------
template <int KC, bool AF32, bool CBF16>
__global__ __launch_bounds__(512) void gemm_mfma(
    const void* __restrict__ Av, const short* __restrict__ WB,
    const float* __restrict__ bias, void* __restrict__ Cv,
    int M, int Keff) {
    constexpr int KPAD  = KC * 32;
    constexpr int CELLS = KPAD / 8;
    __shared__ short As[128 * 256];          // 64 KB
    const int tid = threadIdx.x;
    const int m0 = blockIdx.x * 128;
    const int n0 = blockIdx.y * 192;

    {
        const int row  = tid >> 2;
        const int c0   = (tid & 3) * 8;
        const int rowg = m0 + row;
        const int vcell = Keff >> 3;
        for (int i = 0; i < 8; i++) {
            const int c = c0 + i;
            if (c >= CELLS) break;
            bf16x8 v;
            if (rowg < M && c < vcell) {
                if constexpr (AF32) {
                    const float* ap = (const float*)Av + (size_t)rowg * Keff + c * 8;
                    const float4 x = *(const float4*)ap;
                    const float4 y = *(const float4*)(ap + 4);
                    v[0] = f2b(x.x); v[1] = f2b(x.y); v[2] = f2b(x.z); v[3] = f2b(x.w);
                    v[4] = f2b(y.x); v[5] = f2b(y.y); v[6] = f2b(y.z); v[7] = f2b(y.w);
                } else {
                    const short* ap = (const short*)Av + (size_t)rowg * Keff + c * 8;
                    v = *(const bf16x8*)ap;
                }
            } else {
                v = (bf16x8)(short)0;
            }
            *(bf16x8*)&As[row * 256 + ((c ^ (row & 7)) << 3)] = v;
        }
    }
    __syncthreads();

    const int w  = tid >> 6;
    const int l  = tid & 63;
    const int lr = l & 15, lg = l >> 4;

    bf16x8 af[KC];
    {
        const int row = (w << 4) + lr;
#pragma unroll
        for (int kc = 0; kc < KC; kc++) {
            const int cell = kc * 4 + lg;
            af[kc] = *(const bf16x8*)&As[row * 256 + ((cell ^ (row & 7)) << 3)];
        }
    }
    f32x4 acc[12];
#pragma unroll
    for (int nt = 0; nt < 12; nt++) acc[nt] = (f32x4){0.f, 0.f, 0.f, 0.f};
#pragma unroll
    for (int nt = 0; nt < 12; nt++) {
        const short* wb = WB + (size_t)(n0 + nt * 16 + lr) * KPAD + lg * 8;
#pragma unroll
        for (int kc = 0; kc < KC; kc++) {
            bf16x8 bf = *(const bf16x8*)(wb + kc * 32);
            acc[nt] = __builtin_amdgcn_mfma_f32_16x16x32_bf16(af[kc], bf, acc[nt], 0, 0, 0);
        }
    }
#pragma unroll
    for (int nt = 0; nt < 12; nt++) {
        const int col = n0 + nt * 16 + lr;
        const float bv = bias[col];
#pragma unroll
        for (int q = 0; q < 4; q++) {
            const int row = m0 + (w << 4) + lg * 4 + q;
            if (row < M) {
                const float o = acc[nt][q] + bv;
                if constexpr (CBF16) ((short*)Cv)[(size_t)row * G3 + col] = f2b(o);
                else                 ((float*)Cv)[(size_t)row * G3 + col] = o;
            }
        }
    }
}

// ---------------------------------------------------------------------------
// MFMA GRU, TM=16 seqs/block, block 1024 (16 waves).
// Wave w owns h-columns jj = w*16 + (lane&15). ALL Whh fragments for those
// columns (3 gates x 8 K-chunks = 96 VGPRs) are preloaded into registers
// before the t-loop: zero weight memory traffic per step.
// gx gather: plain VGPR u16 loads, register double-buffered one step ahead;
// barriers are raw s_barrier + lgkmcnt(0) ONLY, so gathers stay in flight
// across barriers (no vmcnt drain).
// h kept f32 in regs; bf16 mirror in XOR-swizzled LDS (hsB) for next step's
// MFMA A-fragments. idx tile staged to LDS once.
// ---------------------------------------------------------------------------
__global__ __launch_bounds__(1024) void gru_mfma(
    const int* __restrict__ idx,        // null => dense rows (n0+s)*T + t
    const short* __restrict__ gxb,      // bf16 row table (P or gx dense), stride 768
    const short* __restrict__ WB,       // [768][256] bf16
    const float* __restrict__ bhh,
    float* __restrict__ hf32,           // optional [N][256]
    short* __restrict__ hb16,           // optional [N][256]
    int T) {
    __shared__ short hsB[16 * 256];     // 8 KB, swizzled bf16 h
    __shared__ int idxs[16 * T1];       // 2 KB token tile
    const int tid = threadIdx.x;
    const int n0 = blockIdx.x * 16;
    const int w  = tid >> 6, l = tid & 63;
    const int lr = l & 15, lg = l >> 4;
    const int jj = w * 16 + lr;         // this lane's h-column

    for (int i = tid; i < 16 * 256; i += 1024) hsB[i] = 0;
    if (idx) {
        for (int i = tid; i < 16 * T; i += 1024) {
            const int s = i / T, p = i - s * T;
            int tk = idx[(size_t)(n0 + s) * T + p];
            idxs[s * T + p] = min(max(tk, 0), VOCAB - 1);
        }
    }

    const float bR = bhh[jj];
    const float bZ = bhh[256 + jj];
    const float bN = bhh[512 + jj];

    // ---- preload all weight fragments (once) ----
    bf16x8 bw[3][8];
#pragma unroll
    for (int g = 0; g < 3; g++) {
        const short* wb = WB + (size_t)(g * 256 + jj) * 256 + lg * 8;
#pragma unroll
        for (int kc = 0; kc < 8; kc++)
            bw[g][kc] = *(const bf16x8*)(wb + kc * 32);
    }

    float hreg[4] = {0.f, 0.f, 0.f, 0.f};
    __syncthreads();   // hsB zeros + idxs visible (one full drain, prologue only)

    // gather: 12 u16 per lane per step (4 rows x 3 gates), reg double-buffer
    unsigned short gA[12], gB[12];
    auto load_gx = [&](unsigned short (&buf)[12], int t) {
#pragma unroll
        for (int q = 0; q < 4; q++) {
            const int s = lg * 4 + q;
            size_t rowbase;
            if (idx) rowbase = (size_t)idxs[s * T + t] * G3;
            else     rowbase = ((size_t)(n0 + s) * T + t) * G3;
            const short* src = gxb + rowbase;
            buf[q * 3 + 0] = *(const unsigned short*)&src[jj];
            buf[q * 3 + 1] = *(const unsigned short*)&src[256 + jj];
            buf[q * 3 + 2] = *(const unsigned short*)&src[512 + jj];
        }
    };
    auto step = [&](const unsigned short (&buf)[12]) {
        // A-fragments from swizzled bf16 h
        bf16x8 af[8];
#pragma unroll
        for (int kc = 0; kc < 8; kc++) {
            const int cell = kc * 4 + lg;
            af[kc] = *(const bf16x8*)&hsB[lr * 256 + ((cell ^ (lr & 7)) << 3)];
        }
        lds_barrier();   // all waves done READING hsB (lgkm only; vmcnt untouched)

        f32x4 acc[3];
#pragma unroll
        for (int g = 0; g < 3; g++) acc[g] = (f32x4){0.f, 0.f, 0.f, 0.f};
#pragma unroll
        for (int g = 0; g < 3; g++)
#pragma unroll
            for (int kc = 0; kc < 8; kc++)
                acc[g] = __builtin_amdgcn_mfma_f32_16x16x32_bf16(af[kc], bw[g][kc], acc[g], 0, 0, 0);

        // phase B: gates in-register; D row=(lg*4+q)=s, col=jj
#pragma unroll
        for (int q = 0; q < 4; q++) {
            const int s = lg * 4 + q;
            const float xr = b2f(buf[q * 3 + 0]);
            const float xz = b2f(buf[q * 3 + 1]);
            const float xn = b2f(buf[q * 3 + 2]);
            const float r = sigmoid_f(xr + acc[0][q] + bR);
            const float z = sigmoid_f(xz + acc[1][q] + bZ);
            const float n = tanh_f(xn + r * (acc[2][q] + bN));
            const float h = (1.f - z) * n + z * hreg[q];
            hreg[q] = h;
            hsB[s * 256 + (((jj >> 3) ^ (s & 7)) << 3) + (jj & 7)] = f2b(h);
        }
        lds_barrier();   // hsB writes visible before next step's reads
    };

    load_gx(gA, 0);
    for (int t = 0; t < T; t += 2) {
        if (t + 1 < T) load_gx(gB, t + 1);   // in flight across barriers
        step(gA);
        if (t + 2 < T) load_gx(gA, t + 2);
        step(gB);
    }

    // epilogue
#pragma unroll
    for (int q = 0; q < 4; q++) {
        const int s = lg * 4 + q;
        const size_t o = (size_t)(n0 + s) * HDIM + jj;
        if (hf32) hf32[o] = hreg[q];
        if (hb16) hb16[o] = f2b(hreg[q]);
    }
}

// ---------------------------------------------------------------------------
// MLP head (f32, tiny)
// ---------------------------------------------------------------------------
__global__ __launch_bounds__(128) void mlp_head(
    const float* __restrict__ hin, const float* __restrict__ W1,
    const float* __restrict__ b1, const float* __restrict__ W2,
    const float* __restrict__ b2, float* __restrict__ out) {
    const int row = blockIdx.x;
    const int gg = threadIdx.x;
    const float* h = hin + (size_t)row * HDIM;
    const float* wv1 = W1 + (size_t)gg * HDIM;
    float acc = 0.f;
#pragma unroll 4
    for (int k = 0; k < HDIM; k += 4) {
        const float4 hv = *(const float4*)&h[k];
        const float4 wv = *(const float4*)&wv1[k];
        acc += hv.x * wv.x; acc += hv.y * wv.y;
        acc += hv.z * wv.z; acc += hv.w * wv.w;
    }
    acc += b1[gg];
    const float alpha = 1.6732632423543772f;
    const float scale = 1.0507009873554805f;
    const float s = scale * (acc > 0.f ? acc : alpha * expm1f(acc));
    float v = s * W2[gg];

    __shared__ float red[128];
    red[gg] = v;
    __syncthreads();
    if (gg < 64) {
        float x = red[gg] + red[gg + 64];
#pragma unroll
        for (int off = 32; off; off >>= 1) x += __shfl_down(x, off);
        if (gg == 0) out[row] = x + b2[0];
    }
}

// ---------------------------------------------------------------------------
extern "C" void kernel_launch(void* const* d_in, const int* in_sizes, int n_in,
                              void* d_out, int out_size, void* d_ws, size_t ws_size,
                              hipStream_t stream) {
    const int*   idx    = (const int*)d_in[0];
    const float* emb    = (const float*)d_in[1];
    const float* w_Wih  = (const float*)d_in[2];
    const float* w_Whh  = (const float*)d_in[3];
    const float* w_bih  = (const float*)d_in[4];
    const float* w_bhh  = (const float*)d_in[5];
    const float* s_Wih  = (const float*)d_in[6];
    const float* s_Whh  = (const float*)d_in[7];
    const float* s_bih  = (const float*)d_in[8];
    const float* s_bhh  = (const float*)d_in[9];
    const float* r_Wih  = (const float*)d_in[10];
    const float* r_Whh  = (const float*)d_in[11];
    const float* r_bih  = (const float*)d_in[12];
    const float* r_bhh  = (const float*)d_in[13];
    const float* rfc_W1 = (const float*)d_in[14];
    const float* rfc_b1 = (const float*)d_in[15];
    const float* rfc_W2 = (const float*)d_in[16];
    const float* rfc_b2 = (const float*)d_in[17];
    const float* pfc_W1 = (const float*)d_in[18];
    const float* pfc_b1 = (const float*)d_in[19];
    const float* pfc_W2 = (const float*)d_in[20];
    const float* pfc_b2 = (const float*)d_in[21];

    float* out = (float*)d_out;      // [0..15] b_stars, [16..271] r_stars

    // ---- workspace layout ----
    short* sws = (short*)d_ws;
    short* Pb      = sws;                                  // 50000*768 bf16
    short* gx2b    = Pb      + (size_t)VOCAB * G3;         // 4096*768
    short* gx3b    = gx2b    + (size_t)NSEQ1 * G3;         // 256*768
    short* WhhB_w  = gx3b    + (size_t)NSEQ2 * G3;         // 768*256
    short* WihB_w  = WhhB_w  + (size_t)G3 * HDIM;          // 768*224
    short* sWihB   = WihB_w  + (size_t)G3 * 224;
    short* sWhhB   = sWihB   + (size_t)G3 * HDIM;
    short* rWihB   = sWhhB   + (size_t)G3 * HDIM;
    short* rWhhB   = rWihB   + (size_t)G3 * HDIM;
    short* sent_hB = rWhhB   + (size_t)G3 * HDIM;          // 4096*256
    short* rev_hB  = sent_hB + (size_t)NSEQ1 * HDIM;       // 256*256
    float* fws     = (float*)(rev_hB + (size_t)NSEQ2 * HDIM);
    float* rev_h   = fws;                                  // 256*256 f32
    float* biz_h   = rev_h + (size_t)NSEQ2 * HDIM;         // 16*256 f32

    // ---- weight conversions: one launch ----
    CvtJobs jobs;
    jobs.j[0] = {w_Whh, WhhB_w, HDIM, HDIM};
    jobs.j[1] = {w_Wih, WihB_w, EDIM, 224};
    jobs.j[2] = {s_Wih, sWihB, HDIM, HDIM};
    jobs.j[3] = {s_Whh, sWhhB, HDIM, HDIM};
    jobs.j[4] = {r_Wih, rWihB, HDIM, HDIM};
    jobs.j[5] = {r_Whh, rWhhB, HDIM, HDIM};
    convert6<<<dim3(G3, 6), 256, 0, stream>>>(jobs);

    // 1) Pb = bf16(emb @ w_Wih^T + w_bih)  [50000 x 768]
    gemm_mfma<7, true, true><<<dim3((VOCAB + 127) / 128, 4), 512, 0, stream>>>(
        emb, WihB_w, w_bih, Pb, VOCAB, EDIM);

    // 2) Word-level GRU (gather): 4096 seqs x 32 steps -> sent_hB
    gru_mfma<<<NSEQ1 / 16, 1024, 0, stream>>>(
        idx, Pb, WhhB_w, w_bhh, nullptr, sent_hB, T1);

    // 3) gx2b = bf16(sent_h @ s_Wih^T + s_bih)  [4096 x 768]
    gemm_mfma<8, false, true><<<dim3(NSEQ1 / 128, 4), 512, 0, stream>>>(
        sent_hB, sWihB, s_bih, gx2b, NSEQ1, HDIM);

    // 4) Sentence-level GRU (dense): 256 seqs x 16 steps -> rev_h(+bf16)
    gru_mfma<<<NSEQ2 / 16, 1024, 0, stream>>>(
        nullptr, gx2b, sWhhB, s_bhh, rev_h, rev_hB, T2);

    // 5) r_stars -> out[16..271]
    mlp_head<<<NSEQ2, 128, 0, stream>>>(
        rev_h, rfc_W1, rfc_b1, rfc_W2, rfc_b2, out + 16);

    // 6) gx3b = bf16(rev_h @ r_Wih^T + r_bih)  [256 x 768]
    gemm_mfma<8, false, true><<<dim3(2, 4), 512, 0, stream>>>(
        rev_hB, rWihB, r_bih, gx3b, NSEQ2, HDIM);

    // 7) Review-level GRU (dense): 16 seqs x 16 steps -> biz_h
    gru_mfma<<<1, 1024, 0, stream>>>(
        nullptr, gx3b, rWhhB, r_bhh, biz_h, nullptr, T3);

    // 8) b_stars -> out[0..15]
    mlp_head<<<NSEQ3, 128, 0, stream>>>(
        biz_h, pfc_W1, pfc_b1, pfc_W2, pfc_b2, out);
}

// Round 7
// 626.773 us; speedup vs baseline: 1.5562x; 1.2126x over previous
//
#include <hip/hip_runtime.h>
#include <math.h>

// Sizes (fixed by the problem)
#define VOCAB 50000
#define EDIM  200
#define HDIM  256
#define G3    768      // 3*H
#define NSEQ1 4096     // B*R*S word sequences
#define T1    32       // W
#define NSEQ2 256      // B*R sentence sequences
#define T2    16       // S
#define NSEQ3 16       // B review sequences
#define T3    16       // R

using bf16x8 = __attribute__((ext_vector_type(8))) short;
using f32x4  = __attribute__((ext_vector_type(4))) float;

__device__ __forceinline__ float sigmoid_f(float x) {
    return 1.0f / (1.0f + __expf(-x));
}
__device__ __forceinline__ float tanh_f(float x) {
    return 1.0f - 2.0f / (__expf(2.0f * x) + 1.0f);
}
// f32 -> bf16 (RNE)
__device__ __forceinline__ short f2b(float f) {
    unsigned u = __float_as_uint(f);
    unsigned r = (u + 0x7fffu + ((u >> 16) & 1u)) >> 16;
    return (short)r;
}
__device__ __forceinline__ float b2f(unsigned short v) {
    return __uint_as_float((unsigned)v << 16);
}
// barrier that drains ONLY lgkmcnt (LDS) — leaves global loads in flight
__device__ __forceinline__ void lds_barrier() {
    asm volatile("s_waitcnt lgkmcnt(0)\n\ts_barrier" ::: "memory");
}

// ---------------------------------------------------------------------------
// Batched f32 -> bf16 conversions (zero-padded): one launch for all 6 weights.
// ---------------------------------------------------------------------------
struct CvtJob { const float* src; short* dst; int kin; int kpad; };
struct CvtJobs { CvtJob j[6]; };

__global__ void convert6(CvtJobs jobs) {
    const CvtJob jb = jobs.j[blockIdx.y];
    const int r = blockIdx.x;
    for (int k = threadIdx.x; k < jb.kpad; k += blockDim.x)
        jb.dst[(size_t)r * jb.kpad + k] =
            (k < jb.kin) ? f2b(jb.src[(size_t)r * jb.kin + k]) : (short)0;
}

// ---------------------------------------------------------------------------
// C[M,768] = A[M,Keff] @ WB[768,KPAD]^T + bias  via bf16 MFMA.
// KC=KPAD/32. AF32: A f32 (else bf16). CBF16: C bf16 (else f32).
// Block 512 (8 waves), wave = M-tile, 12 N-tiles. grid (ceil(M/128), 4).
// ---------------------------------------------------------------------------
template <int KC, bool AF32, bool CBF16>
__global__ __launch_bounds__(512) void gemm_mfma(
    const void* __restrict__ Av, const short* __restrict__ WB,
    const float* __restrict__ bias, void* __restrict__ Cv,
    int M, int Keff) {
    constexpr int KPAD  = KC * 32;
    constexpr int CELLS = KPAD / 8;
    __shared__ short As[128 * 256];          // 64 KB
    const int tid = threadIdx.x;
    const int m0 = blockIdx.x * 128;
    const int n0 = blockIdx.y * 192;

    {
        const int row  = tid >> 2;
        const int c0   = (tid & 3) * 8;
        const int rowg = m0 + row;
        const int vcell = Keff >> 3;
        for (int i = 0; i < 8; i++) {
            const int c = c0 + i;
            if (c >= CELLS) break;
            bf16x8 v;
            if (rowg < M && c < vcell) {
                if constexpr (AF32) {
                    const float* ap = (const float*)Av + (size_t)rowg * Keff + c * 8;
                    const float4 x = *(const float4*)ap;
                    const float4 y = *(const float4*)(ap + 4);
                    v[0] = f2b(x.x); v[1] = f2b(x.y); v[2] = f2b(x.z); v[3] = f2b(x.w);
                    v[4] = f2b(y.x); v[5] = f2b(y.y); v[6] = f2b(y.z); v[7] = f2b(y.w);
                } else {
                    const short* ap = (const short*)Av + (size_t)rowg * Keff + c * 8;
                    v = *(const bf16x8*)ap;
                }
            } else {
                v = (bf16x8)(short)0;
            }
            *(bf16x8*)&As[row * 256 + ((c ^ (row & 7)) << 3)] = v;
        }
    }
    __syncthreads();

    const int w  = tid >> 6;
    const int l  = tid & 63;
    const int lr = l & 15, lg = l >> 4;

    bf16x8 af[KC];
    {
        const int row = (w << 4) + lr;
#pragma unroll
        for (int kc = 0; kc < KC; kc++) {
            const int cell = kc * 4 + lg;
            af[kc] = *(const bf16x8*)&As[row * 256 + ((cell ^ (row & 7)) << 3)];
        }
    }
    f32x4 acc[12];
#pragma unroll
    for (int nt = 0; nt < 12; nt++) acc[nt] = (f32x4){0.f, 0.f, 0.f, 0.f};
#pragma unroll
    for (int nt = 0; nt < 12; nt++) {
        const short* wb = WB + (size_t)(n0 + nt * 16 + lr) * KPAD + lg * 8;
#pragma unroll
        for (int kc = 0; kc < KC; kc++) {
            bf16x8 bf = *(const bf16x8*)(wb + kc * 32);
            acc[nt] = __builtin_amdgcn_mfma_f32_16x16x32_bf16(af[kc], bf, acc[nt], 0, 0, 0);
        }
    }
#pragma unroll
    for (int nt = 0; nt < 12; nt++) {
        const int col = n0 + nt * 16 + lr;
        const float bv = bias[col];
#pragma unroll
        for (int q = 0; q < 4; q++) {
            const int row = m0 + (w << 4) + lg * 4 + q;
            if (row < M) {
                const float o = acc[nt][q] + bv;
                if constexpr (CBF16) ((short*)Cv)[(size_t)row * G3 + col] = f2b(o);
                else                 ((float*)Cv)[(size_t)row * G3 + col] = o;
            }
        }
    }
}

// ---------------------------------------------------------------------------
// MFMA GRU, TM=16 seqs/block, block 512 (8 waves), 1 block/CU.
// Wave w owns 32 h-columns (triples tt0=2w, tt0+1).
// r,z gate weights: REGISTER-resident (2 triples x 2 gates x 8 kc = 128 VGPR).
// n gate weights:   LDS-resident (256x256 bf16 = 131 KB, XOR-swizzled),
//                   loaded once in the prologue.
// => zero per-step global weight traffic.
// gx gather: plain u16 loads packed into u32 pairs, register double-buffered
// one step ahead; barriers are s_barrier + lgkmcnt(0) only (vmcnt untouched).
// h kept f32 in regs; bf16 mirror in XOR-swizzled LDS (hsB).
// ---------------------------------------------------------------------------
__global__ __launch_bounds__(512, 2) void gru_mfma(
    const int* __restrict__ idx,        // null => dense rows (n0+s)*T + t
    const short* __restrict__ gxb,      // bf16 row table (P or gx dense), stride 768
    const short* __restrict__ WB,       // [768][256] bf16
    const float* __restrict__ bhh,
    float* __restrict__ hf32,           // optional [N][256]
    short* __restrict__ hb16,           // optional [N][256]
    int T) {
    __shared__ short wsN[256 * 256 / 2 * 2];   // 256 rows x 256 cols bf16 = 131072 B
    __shared__ short hsB[16 * 256];            // 8 KB, swizzled bf16 h
    __shared__ int idxs[16 * T1];              // 2 KB token tile
    const int tid = threadIdx.x;
    const int n0 = blockIdx.x * 16;
    const int w  = tid >> 6, l = tid & 63;
    const int lr = l & 15, lg = l >> 4;
    const int tt0 = w * 2;
    const int jj0 = tt0 * 16 + lr;       // first owned column
    const int jj1 = jj0 + 16;            // second owned column

    // ---- prologue: hsB zeros, idx tile, n-gate weights -> LDS ----
    for (int i = tid; i < 16 * 256; i += 512) hsB[i] = 0;
    if (idx) {
        for (int i = tid; i < 16 * T; i += 512) {
            const int s = i / T, p = i - s * T;
            int tk = idx[(size_t)(n0 + s) * T + p];
            idxs[s * T + p] = min(max(tk, 0), VOCAB - 1);
        }
    }
#pragma unroll
    for (int i = 0; i < 16; i++) {
        const int cellidx = tid * 16 + i;     // 0..8191
        const int rr = cellidx >> 5;          // 0..255 (n-gate row = h column)
        const int cc = cellidx & 31;          // cell (8 shorts)
        bf16x8 v = *(const bf16x8*)&WB[(size_t)(512 + rr) * 256 + cc * 8];
        *(bf16x8*)&wsN[rr * 256 + ((cc ^ (rr & 7)) << 3)] = v;
    }

    // ---- r,z weights -> registers (128 VGPRs), loaded once ----
    bf16x8 bwR[2][8], bwZ[2][8];
#pragma unroll
    for (int ti = 0; ti < 2; ti++) {
        const int jjt = (tt0 + ti) * 16 + lr;
#pragma unroll
        for (int kc = 0; kc < 8; kc++) {
            bwR[ti][kc] = *(const bf16x8*)&WB[(size_t)jjt * 256 + kc * 32 + lg * 8];
            bwZ[ti][kc] = *(const bf16x8*)&WB[(size_t)(256 + jjt) * 256 + kc * 32 + lg * 8];
        }
    }
    const float bR0 = bhh[jj0],       bR1 = bhh[jj1];
    const float bZ0 = bhh[256 + jj0], bZ1 = bhh[256 + jj1];
    const float bN0 = bhh[512 + jj0], bN1 = bhh[512 + jj1];

    float hreg[2][4] = {};
    __syncthreads();   // prologue full drain (once)

    // gather: per step 24 u16 (4 rows x 3 gates x 2 cols), packed to 12 u32
    unsigned gA[12], gB[12];
    auto load_gx = [&](unsigned (&buf)[12], int t) {
#pragma unroll
        for (int q = 0; q < 4; q++) {
            const int s = lg * 4 + q;
            size_t rowbase;
            if (idx) rowbase = (size_t)idxs[s * T + t] * G3;
            else     rowbase = ((size_t)(n0 + s) * T + t) * G3;
            const unsigned short* src = (const unsigned short*)(gxb + rowbase);
            const unsigned xr0 = src[jj0],       xr1 = src[jj1];
            const unsigned xz0 = src[256 + jj0], xz1 = src[256 + jj1];
            const unsigned xn0 = src[512 + jj0], xn1 = src[512 + jj1];
            buf[q * 3 + 0] = xr0 | (xz0 << 16);
            buf[q * 3 + 1] = xr1 | (xz1 << 16);
            buf[q * 3 + 2] = xn0 | (xn1 << 16);
        }
    };

    auto step = [&](const unsigned (&buf)[12]) {
        f32x4 aR[2], aZ[2], aN[2];
#pragma unroll
        for (int ti = 0; ti < 2; ti++) {
            aR[ti] = (f32x4){0.f, 0.f, 0.f, 0.f};
            aZ[ti] = (f32x4){0.f, 0.f, 0.f, 0.f};
            aN[ti] = (f32x4){0.f, 0.f, 0.f, 0.f};
        }
        // kc loop: 1 hsB read + 2 wsN reads + 6 MFMAs per kc
#pragma unroll
        for (int kc = 0; kc < 8; kc++) {
            const int cell = kc * 4 + lg;
            const bf16x8 a  = *(const bf16x8*)&hsB[lr * 256 + ((cell ^ (lr & 7)) << 3)];
            const bf16x8 n0f = *(const bf16x8*)&wsN[jj0 * 256 + ((cell ^ (jj0 & 7)) << 3)];
            const bf16x8 n1f = *(const bf16x8*)&wsN[jj1 * 256 + ((cell ^ (jj1 & 7)) << 3)];
            aR[0] = __builtin_amdgcn_mfma_f32_16x16x32_bf16(a, bwR[0][kc], aR[0], 0, 0, 0);
            aZ[0] = __builtin_amdgcn_mfma_f32_16x16x32_bf16(a, bwZ[0][kc], aZ[0], 0, 0, 0);
            aN[0] = __builtin_amdgcn_mfma_f32_16x16x32_bf16(a, n0f, aN[0], 0, 0, 0);
            aR[1] = __builtin_amdgcn_mfma_f32_16x16x32_bf16(a, bwR[1][kc], aR[1], 0, 0, 0);
            aZ[1] = __builtin_amdgcn_mfma_f32_16x16x32_bf16(a, bwZ[1][kc], aZ[1], 0, 0, 0);
            aN[1] = __builtin_amdgcn_mfma_f32_16x16x32_bf16(a, n1f, aN[1], 0, 0, 0);
        }
        lds_barrier();   // everyone done READING hsB (lgkm only)

        // phase B: in-register gates; D row=(lg*4+q)=s, col=jj{0,1}
#pragma unroll
        for (int q = 0; q < 4; q++) {
            const int s = lg * 4 + q;
            const unsigned prz0 = buf[q * 3 + 0];
            const unsigned prz1 = buf[q * 3 + 1];
            const unsigned pn   = buf[q * 3 + 2];
            {   // triple 0
                const float xr = b2f((unsigned short)(prz0 & 0xffff));
                const float xz = b2f((unsigned short)(prz0 >> 16));
                const float xn = b2f((unsigned short)(pn & 0xffff));
                const float r = sigmoid_f(xr + aR[0][q] + bR0);
                const float z = sigmoid_f(xz + aZ[0][q] + bZ0);
                const float n = tanh_f(xn + r * (aN[0][q] + bN0));
                const float h = (1.f - z) * n + z * hreg[0][q];
                hreg[0][q] = h;
                hsB[s * 256 + (((jj0 >> 3) ^ (s & 7)) << 3) + (jj0 & 7)] = f2b(h);
            }
            {   // triple 1
                const float xr = b2f((unsigned short)(prz1 & 0xffff));
                const float xz = b2f((unsigned short)(prz1 >> 16));
                const float xn = b2f((unsigned short)(pn >> 16));
                const float r = sigmoid_f(xr + aR[1][q] + bR1);
                const float z = sigmoid_f(xz + aZ[1][q] + bZ1);
                const float n = tanh_f(xn + r * (aN[1][q] + bN1));
                const float h = (1.f - z) * n + z * hreg[1][q];
                hreg[1][q] = h;
                hsB[s * 256 + (((jj1 >> 3) ^ (s & 7)) << 3) + (jj1 & 7)] = f2b(h);
            }
        }
        lds_barrier();   // hsB writes visible before next step's reads
    };

    load_gx(gA, 0);
    for (int t = 0; t < T; t += 2) {
        if (t + 1 < T) load_gx(gB, t + 1);   // in flight across barriers
        step(gA);
        if (t + 2 < T) load_gx(gA, t + 2);
        step(gB);
    }

    // epilogue
#pragma unroll
    for (int q = 0; q < 4; q++) {
        const int s = lg * 4 + q;
        const size_t o0 = (size_t)(n0 + s) * HDIM + jj0;
        const size_t o1 = (size_t)(n0 + s) * HDIM + jj1;
        if (hf32) { hf32[o0] = hreg[0][q]; hf32[o1] = hreg[1][q]; }
        if (hb16) { hb16[o0] = f2b(hreg[0][q]); hb16[o1] = f2b(hreg[1][q]); }
    }
}

// ---------------------------------------------------------------------------
// MLP head (f32, tiny)
// ---------------------------------------------------------------------------
__global__ __launch_bounds__(128) void mlp_head(
    const float* __restrict__ hin, const float* __restrict__ W1,
    const float* __restrict__ b1, const float* __restrict__ W2,
    const float* __restrict__ b2, float* __restrict__ out) {
    const int row = blockIdx.x;
    const int gg = threadIdx.x;
    const float* h = hin + (size_t)row * HDIM;
    const float* wv1 = W1 + (size_t)gg * HDIM;
    float acc = 0.f;
#pragma unroll 4
    for (int k = 0; k < HDIM; k += 4) {
        const float4 hv = *(const float4*)&h[k];
        const float4 wv = *(const float4*)&wv1[k];
        acc += hv.x * wv.x; acc += hv.y * wv.y;
        acc += hv.z * wv.z; acc += hv.w * wv.w;
    }
    acc += b1[gg];
    const float alpha = 1.6732632423543772f;
    const float scale = 1.0507009873554805f;
    const float s = scale * (acc > 0.f ? acc : alpha * expm1f(acc));
    float v = s * W2[gg];

    __shared__ float red[128];
    red[gg] = v;
    __syncthreads();
    if (gg < 64) {
        float x = red[gg] + red[gg + 64];
#pragma unroll
        for (int off = 32; off; off >>= 1) x += __shfl_down(x, off);
        if (gg == 0) out[row] = x + b2[0];
    }
}

// ---------------------------------------------------------------------------
extern "C" void kernel_launch(void* const* d_in, const int* in_sizes, int n_in,
                              void* d_out, int out_size, void* d_ws, size_t ws_size,
                              hipStream_t stream) {
    const int*   idx    = (const int*)d_in[0];
    const float* emb    = (const float*)d_in[1];
    const float* w_Wih  = (const float*)d_in[2];
    const float* w_Whh  = (const float*)d_in[3];
    const float* w_bih  = (const float*)d_in[4];
    const float* w_bhh  = (const float*)d_in[5];
    const float* s_Wih  = (const float*)d_in[6];
    const float* s_Whh  = (const float*)d_in[7];
    const float* s_bih  = (const float*)d_in[8];
    const float* s_bhh  = (const float*)d_in[9];
    const float* r_Wih  = (const float*)d_in[10];
    const float* r_Whh  = (const float*)d_in[11];
    const float* r_bih  = (const float*)d_in[12];
    const float* r_bhh  = (const float*)d_in[13];
    const float* rfc_W1 = (const float*)d_in[14];
    const float* rfc_b1 = (const float*)d_in[15];
    const float* rfc_W2 = (const float*)d_in[16];
    const float* rfc_b2 = (const float*)d_in[17];
    const float* pfc_W1 = (const float*)d_in[18];
    const float* pfc_b1 = (const float*)d_in[19];
    const float* pfc_W2 = (const float*)d_in[20];
    const float* pfc_b2 = (const float*)d_in[21];

    float* out = (float*)d_out;      // [0..15] b_stars, [16..271] r_stars

    // ---- workspace layout ----
    short* sws = (short*)d_ws;
    short* Pb      = sws;                                  // 50000*768 bf16
    short* gx2b    = Pb      + (size_t)VOCAB * G3;         // 4096*768
    short* gx3b    = gx2b    + (size_t)NSEQ1 * G3;         // 256*768
    short* WhhB_w  = gx3b    + (size_t)NSEQ2 * G3;         // 768*256
    short* WihB_w  = WhhB_w  + (size_t)G3 * HDIM;          // 768*224
    short* sWihB   = WihB_w  + (size_t)G3 * 224;
    short* sWhhB   = sWihB   + (size_t)G3 * HDIM;
    short* rWihB   = sWhhB   + (size_t)G3 * HDIM;
    short* rWhhB   = rWihB   + (size_t)G3 * HDIM;
    short* sent_hB = rWhhB   + (size_t)G3 * HDIM;          // 4096*256
    short* rev_hB  = sent_hB + (size_t)NSEQ1 * HDIM;       // 256*256
    float* fws     = (float*)(rev_hB + (size_t)NSEQ2 * HDIM);
    float* rev_h   = fws;                                  // 256*256 f32
    float* biz_h   = rev_h + (size_t)NSEQ2 * HDIM;         // 16*256 f32

    // ---- weight conversions: one launch ----
    CvtJobs jobs;
    jobs.j[0] = {w_Whh, WhhB_w, HDIM, HDIM};
    jobs.j[1] = {w_Wih, WihB_w, EDIM, 224};
    jobs.j[2] = {s_Wih, sWihB, HDIM, HDIM};
    jobs.j[3] = {s_Whh, sWhhB, HDIM, HDIM};
    jobs.j[4] = {r_Wih, rWihB, HDIM, HDIM};
    jobs.j[5] = {r_Whh, rWhhB, HDIM, HDIM};
    convert6<<<dim3(G3, 6), 256, 0, stream>>>(jobs);

    // 1) Pb = bf16(emb @ w_Wih^T + w_bih)  [50000 x 768]
    gemm_mfma<7, true, true><<<dim3((VOCAB + 127) / 128, 4), 512, 0, stream>>>(
        emb, WihB_w, w_bih, Pb, VOCAB, EDIM);

    // 2) Word-level GRU (gather): 4096 seqs x 32 steps -> sent_hB
    gru_mfma<<<NSEQ1 / 16, 512, 0, stream>>>(
        idx, Pb, WhhB_w, w_bhh, nullptr, sent_hB, T1);

    // 3) gx2b = bf16(sent_h @ s_Wih^T + s_bih)  [4096 x 768]
    gemm_mfma<8, false, true><<<dim3(NSEQ1 / 128, 4), 512, 0, stream>>>(
        sent_hB, sWihB, s_bih, gx2b, NSEQ1, HDIM);

    // 4) Sentence-level GRU (dense): 256 seqs x 16 steps -> rev_h(+bf16)
    gru_mfma<<<NSEQ2 / 16, 512, 0, stream>>>(
        nullptr, gx2b, sWhhB, s_bhh, rev_h, rev_hB, T2);

    // 5) r_stars -> out[16..271]
    mlp_head<<<NSEQ2, 128, 0, stream>>>(
        rev_h, rfc_W1, rfc_b1, rfc_W2, rfc_b2, out + 16);

    // 6) gx3b = bf16(rev_h @ r_Wih^T + r_bih)  [256 x 768]
    gemm_mfma<8, false, true><<<dim3(2, 4), 512, 0, stream>>>(
        rev_hB, rWihB, r_bih, gx3b, NSEQ2, HDIM);

    // 7) Review-level GRU (dense): 16 seqs x 16 steps -> biz_h
    gru_mfma<<<1, 512, 0, stream>>>(
        nullptr, gx3b, rWhhB, r_bhh, biz_h, nullptr, T3);

    // 8) b_stars -> out[0..15]
    mlp_head<<<NSEQ3, 128, 0, stream>>>(
        biz_h, pfc_W1, pfc_b1, pfc_W2, pfc_b2, out);
}